// Round 2
// baseline (464.248 us; speedup 1.0000x reference)
//
#include <hip/hip_runtime.h>

#define THRESH 0.05f

typedef __attribute__((ext_vector_type(4))) int int32x4;

// ---------------------------------------------------------------------------
// Kernel 1: quantize weight [1024,1024] fp32 -> int8 {-1,0,+1} into d_ws.
// ---------------------------------------------------------------------------
__global__ __launch_bounds__(256) void quant_w_kernel(const float* __restrict__ w,
                                                      int* __restrict__ wq) {
    int idx = blockIdx.x * 256 + threadIdx.x;   // float4 index
    const float4* w4 = (const float4*)w;
    float4 f = w4[idx];
    int q0 = (f.x >= THRESH) - (f.x <= -THRESH);
    int q1 = (f.y >= THRESH) - (f.y <= -THRESH);
    int q2 = (f.z >= THRESH) - (f.z <= -THRESH);
    int q3 = (f.w >= THRESH) - (f.w <= -THRESH);
    wq[idx] = (q0 & 0xff) | ((q1 & 0xff) << 8) | ((q2 & 0xff) << 16) | ((q3 & 0xff) << 24);
}

// ---------------------------------------------------------------------------
// Kernel 2: slab-resident ternary GEMM.
// Block = 512 threads (8 waves) x 64-row slab x all 1024 cols.
// Phase 1: quantize 64x1024 fp32 x-slab into 64 KB LDS int8 (XOR-swizzled).
// Phase 2: each wave covers 128 cols (2 col-tiles of 64); per tile, 16
// K-steps of 4x4 mfma_i32_16x16x64_i8 with OPERANDS SWAPPED (B as first arg)
// so the D layout gives each lane 4 consecutive output cols -> float4 stores.
// 16 waves/CU (2 blocks x 8 waves) for latency hiding; VGPR capped at 128.
// ---------------------------------------------------------------------------
__global__ __launch_bounds__(512, 4) void tern_gemm_kernel(const float* __restrict__ x,
                                                           const signed char* __restrict__ wq,
                                                           float* __restrict__ out) {
    __shared__ __attribute__((aligned(16))) signed char a_lds[64 * 1024];
    const int tid = threadIdx.x;
    const long rowbase = (long)blockIdx.x * 64;

    // ---- Phase 1: stage + quantize x slab (64 rows x 1024 K) ----
    // 4096 16-byte chunks, 8 per thread; coalesced float4 reads.
    #pragma unroll
    for (int i = 0; i < 8; ++i) {
        int c   = tid + i * 512;   // chunk id 0..4095
        int row = c >> 6;          // 64 chunks per row
        int cir = c & 63;          // chunk-in-row
        const float4* src = (const float4*)(x + (rowbase + row) * 1024 + cir * 16);
        signed char q[16];
        #pragma unroll
        for (int j = 0; j < 4; ++j) {
            float4 f = src[j];
            q[j * 4 + 0] = (signed char)((f.x >= THRESH) - (f.x <= -THRESH));
            q[j * 4 + 1] = (signed char)((f.y >= THRESH) - (f.y <= -THRESH));
            q[j * 4 + 2] = (signed char)((f.z >= THRESH) - (f.z <= -THRESH));
            q[j * 4 + 3] = (signed char)((f.w >= THRESH) - (f.w <= -THRESH));
        }
        int swz = (cir ^ (row & 7)) * 16;  // XOR swizzle: uniform bank spread
        *(int32x4*)(a_lds + row * 1024 + swz) = *(const int32x4*)q;
    }
    __syncthreads();

    // ---- Phase 2: compute ----
    const int wave = tid >> 6;    // 0..7
    const int lane = tid & 63;
    const int l15  = lane & 15;
    const int lq   = lane >> 4;   // lane quarter: selects contiguous K/4 chunk

    for (int ct = 0; ct < 2; ++ct) {
        const int cb = wave * 128 + ct * 64;   // this wave's 64-col tile base
        int32x4 acc[4][4];
        #pragma unroll
        for (int ri = 0; ri < 4; ++ri)
            #pragma unroll
            for (int ci = 0; ci < 4; ++ci)
                acc[ri][ci] = (int32x4){0, 0, 0, 0};

        for (int k = 0; k < 16; ++k) {          // K-steps of 64
            const int kchunk = k * 4 + lq;      // 16B chunk index along K

            int32x4 afrag[4];
            #pragma unroll
            for (int ri = 0; ri < 4; ++ri) {
                int m = ri * 16 + l15;
                afrag[ri] = *(const int32x4*)(a_lds + m * 1024 + ((kchunk ^ (m & 7)) * 16));
            }

            int32x4 bfrag[4];
            #pragma unroll
            for (int ci = 0; ci < 4; ++ci) {
                long col = cb + ci * 16 + l15;
                bfrag[ci] = *(const int32x4*)(wq + col * 1024 + kchunk * 16);
            }

            // swapped operands: D "col"(lane&15) = out ROW, D "row"(quad*4+reg) = out COL
            #pragma unroll
            for (int ri = 0; ri < 4; ++ri)
                #pragma unroll
                for (int ci = 0; ci < 4; ++ci)
                    acc[ri][ci] = __builtin_amdgcn_mfma_i32_16x16x64_i8(
                        bfrag[ci], afrag[ri], acc[ri][ci], 0, 0, 0);
        }

        // ---- epilogue: lane owns 4 consecutive cols -> float4 stores ----
        #pragma unroll
        for (int ri = 0; ri < 4; ++ri) {
            const long row = rowbase + ri * 16 + l15;
            float4 v[4];
            #pragma unroll
            for (int ci = 0; ci < 4; ++ci) {
                v[ci].x = (float)acc[ri][ci][0];
                v[ci].y = (float)acc[ri][ci][1];
                v[ci].z = (float)acc[ri][ci][2];
                v[ci].w = (float)acc[ri][ci][3];
            }
            // stores back-to-back so adjacent 64B half-lines can merge in TCC
            #pragma unroll
            for (int ci = 0; ci < 4; ++ci) {
                const int col = cb + ci * 16 + lq * 4;
                *(float4*)(out + row * 1024 + col) = v[ci];
            }
        }
    }
}

extern "C" void kernel_launch(void* const* d_in, const int* in_sizes, int n_in,
                              void* d_out, int out_size, void* d_ws, size_t ws_size,
                              hipStream_t stream) {
    const float* x = (const float*)d_in[0];      // [32768, 1024] fp32
    const float* w = (const float*)d_in[1];      // [1024, 1024] fp32
    float* out = (float*)d_out;                  // [32768, 1024] fp32
    signed char* wq = (signed char*)d_ws;        // 1 MB int8 scratch

    quant_w_kernel<<<dim3(1024), dim3(256), 0, stream>>>(w, (int*)wq);
    // 32768 rows / 64 = 512 blocks (2 per CU), 8 waves each
    tern_gemm_kernel<<<dim3(512), dim3(512), 0, stream>>>(x, wq, out);
}

// Round 3
// 329.842 us; speedup vs baseline: 1.4075x; 1.4075x over previous
//
#include <hip/hip_runtime.h>

#define THRESH 0.05f

typedef __attribute__((ext_vector_type(4))) int int32x4;

// ---------------------------------------------------------------------------
// Kernel 1: quantize weight [1024,1024] fp32 -> int8 {-1,0,+1} in FRAGMENT
// ORDER: for k-step kb (64-K chunk) and 16-col tile nb, a 1 KB block holds
// [quad][l15][16 K-bytes] so a wave's B-fragment load is lane-contiguous.
//   wqf[(kb*64 + nb)*1024 + lane*16 + j] = tern(w[nb*16 + (lane&15)][kb*64 + (lane>>4)*16 + j])
// ---------------------------------------------------------------------------
__global__ __launch_bounds__(256) void quant_w_kernel(const float* __restrict__ w,
                                                      signed char* __restrict__ wqf) {
    int c = blockIdx.x * 256 + threadIdx.x;   // 16-byte chunk id, 0..65535
    int l15  = c & 15;
    int quad = (c >> 4) & 3;
    int nb   = (c >> 6) & 63;
    int kb   = c >> 12;
    int col   = nb * 16 + l15;
    int kbase = kb * 64 + quad * 16;
    const float* src = w + col * 1024 + kbase;
    signed char q[16];
    #pragma unroll
    for (int j = 0; j < 4; ++j) {
        float4 f = *(const float4*)(src + j * 4);
        q[j * 4 + 0] = (signed char)((f.x >= THRESH) - (f.x <= -THRESH));
        q[j * 4 + 1] = (signed char)((f.y >= THRESH) - (f.y <= -THRESH));
        q[j * 4 + 2] = (signed char)((f.z >= THRESH) - (f.z <= -THRESH));
        q[j * 4 + 3] = (signed char)((f.w >= THRESH) - (f.w <= -THRESH));
    }
    *(int32x4*)(wqf + (size_t)c * 16) = *(const int32x4*)q;
}

// ---------------------------------------------------------------------------
// Kernel 2: slab-resident ternary GEMM.
// Block = 256 threads (4 waves) x 32-row slab x all 1024 cols. 32 KB LDS ->
// 4 blocks/CU (grid 1024 = exactly 4/CU), 16 waves/CU for latency hiding.
// Phase 1: quantize 32x1024 fp32 x-slab into LDS int8 (XOR-swizzled).
// Phase 2: each wave covers 256 cols (4 tiles of 64); 16 K-steps of
// 2x4 mfma_i32_16x16x64_i8, operands swapped so each lane owns 4
// consecutive out cols -> float4 stores. B-frags are single coalesced
// 1 KB loads from the fragment-ordered wqf (L2-resident, 1 MB).
// ---------------------------------------------------------------------------
__global__ __launch_bounds__(256, 4) void tern_gemm_kernel(const float* __restrict__ x,
                                                           const signed char* __restrict__ wqf,
                                                           float* __restrict__ out) {
    __shared__ __attribute__((aligned(16))) signed char a_lds[32 * 1024];
    const int tid = threadIdx.x;
    const long rowbase = (long)blockIdx.x * 32;

    // ---- Phase 1: stage + quantize x slab (32 rows x 1024 K) ----
    // 2048 16-byte chunks, 8 per thread; coalesced float4 reads.
    #pragma unroll
    for (int i = 0; i < 8; ++i) {
        int c   = tid + i * 256;   // chunk id 0..2047
        int row = c >> 6;          // 64 chunks per row
        int cir = c & 63;          // chunk-in-row
        const float4* src = (const float4*)(x + (rowbase + row) * 1024 + cir * 16);
        signed char q[16];
        #pragma unroll
        for (int j = 0; j < 4; ++j) {
            float4 f = src[j];
            q[j * 4 + 0] = (signed char)((f.x >= THRESH) - (f.x <= -THRESH));
            q[j * 4 + 1] = (signed char)((f.y >= THRESH) - (f.y <= -THRESH));
            q[j * 4 + 2] = (signed char)((f.z >= THRESH) - (f.z <= -THRESH));
            q[j * 4 + 3] = (signed char)((f.w >= THRESH) - (f.w <= -THRESH));
        }
        int swz = (cir ^ (row & 7)) * 16;  // XOR swizzle: uniform bank spread
        *(int32x4*)(a_lds + row * 1024 + swz) = *(const int32x4*)q;
    }
    __syncthreads();

    // ---- Phase 2: compute ----
    const int wave = tid >> 6;    // 0..3
    const int lane = tid & 63;
    const int l15  = lane & 15;
    const int lq   = lane >> 4;   // lane quarter

    for (int ct = 0; ct < 4; ++ct) {
        const int cb = wave * 256 + ct * 64;   // this wave's 64-col tile base
        const int nb_base = cb >> 4;           // 16-col tile index base
        int32x4 acc[2][4];
        #pragma unroll
        for (int ri = 0; ri < 2; ++ri)
            #pragma unroll
            for (int ci = 0; ci < 4; ++ci)
                acc[ri][ci] = (int32x4){0, 0, 0, 0};

        for (int k = 0; k < 16; ++k) {          // K-steps of 64
            const int kchunk = k * 4 + lq;      // 16B chunk index along K

            int32x4 afrag[2];
            #pragma unroll
            for (int ri = 0; ri < 2; ++ri) {
                int m = ri * 16 + l15;
                afrag[ri] = *(const int32x4*)(a_lds + m * 1024 + ((kchunk ^ (m & 7)) * 16));
            }

            int32x4 bfrag[4];
            #pragma unroll
            for (int ci = 0; ci < 4; ++ci) {
                // fragment-ordered: 1 KB block per (k, 16-col tile), lane-contiguous
                bfrag[ci] = *(const int32x4*)(wqf + (size_t)(k * 64 + nb_base + ci) * 1024 + lane * 16);
            }

            // swapped operands: D first-idx (quad*4+reg) = out COL, second-idx (lane&15) = out ROW
            #pragma unroll
            for (int ri = 0; ri < 2; ++ri)
                #pragma unroll
                for (int ci = 0; ci < 4; ++ci)
                    acc[ri][ci] = __builtin_amdgcn_mfma_i32_16x16x64_i8(
                        bfrag[ci], afrag[ri], acc[ri][ci], 0, 0, 0);
        }

        // ---- epilogue: lane owns 4 consecutive cols -> float4 stores ----
        #pragma unroll
        for (int ri = 0; ri < 2; ++ri) {
            const long row = rowbase + ri * 16 + l15;
            #pragma unroll
            for (int ci = 0; ci < 4; ++ci) {
                float4 v;
                v.x = (float)acc[ri][ci][0];
                v.y = (float)acc[ri][ci][1];
                v.z = (float)acc[ri][ci][2];
                v.w = (float)acc[ri][ci][3];
                const int col = cb + ci * 16 + lq * 4;
                *(float4*)(out + row * 1024 + col) = v;
            }
        }
    }
}

extern "C" void kernel_launch(void* const* d_in, const int* in_sizes, int n_in,
                              void* d_out, int out_size, void* d_ws, size_t ws_size,
                              hipStream_t stream) {
    const float* x = (const float*)d_in[0];      // [32768, 1024] fp32
    const float* w = (const float*)d_in[1];      // [1024, 1024] fp32
    float* out = (float*)d_out;                  // [32768, 1024] fp32
    signed char* wqf = (signed char*)d_ws;       // 1 MB int8 scratch (fragment order)

    quant_w_kernel<<<dim3(256), dim3(256), 0, stream>>>(w, wqf);
    // 32768 rows / 32 = 1024 blocks (4 per CU), 4 waves each
    tern_gemm_kernel<<<dim3(1024), dim3(256), 0, stream>>>(x, wqf, out);
}

// Round 4
// 288.120 us; speedup vs baseline: 1.6113x; 1.1448x over previous
//
#include <hip/hip_runtime.h>

#define THRESH 0.05f

typedef __attribute__((ext_vector_type(4))) int   int32x4;
typedef __attribute__((ext_vector_type(4))) float floatx4;

// ---------------------------------------------------------------------------
// Kernel 1: quantize weight [1024,1024] fp32 -> int8 {-1,0,+1} in FRAGMENT
// ORDER: for k-step kb (64-K chunk) and 16-col tile nb, a 1 KB block holds
// [quad][l15][16 K-bytes] so a wave's B-fragment load is lane-contiguous.
// ---------------------------------------------------------------------------
__global__ __launch_bounds__(256) void quant_w_kernel(const float* __restrict__ w,
                                                      signed char* __restrict__ wqf) {
    int c = blockIdx.x * 256 + threadIdx.x;   // 16-byte chunk id, 0..65535
    int l15  = c & 15;
    int quad = (c >> 4) & 3;
    int nb   = (c >> 6) & 63;
    int kb   = c >> 12;
    int col   = nb * 16 + l15;
    int kbase = kb * 64 + quad * 16;
    const float* src = w + col * 1024 + kbase;
    signed char q[16];
    #pragma unroll
    for (int j = 0; j < 4; ++j) {
        float4 f = *(const float4*)(src + j * 4);
        q[j * 4 + 0] = (signed char)((f.x >= THRESH) - (f.x <= -THRESH));
        q[j * 4 + 1] = (signed char)((f.y >= THRESH) - (f.y <= -THRESH));
        q[j * 4 + 2] = (signed char)((f.z >= THRESH) - (f.z <= -THRESH));
        q[j * 4 + 3] = (signed char)((f.w >= THRESH) - (f.w <= -THRESH));
    }
    *(int32x4*)(wqf + (size_t)c * 16) = *(const int32x4*)q;
}

// ---------------------------------------------------------------------------
// Kernel 2: slab-resident ternary GEMM, register-resident B.
// Block = 256 threads (4 waves) x 32-row slab x all 1024 cols; 32 KB LDS,
// grid 1024 -> 4 blocks/CU, 16 waves/CU.
// Per col-iter (16 of them): each wave owns a 16-col tile and loads ALL 16
// K-step B-fragments into 64 VGPRs up-front (independent coalesced 1 KB
// loads -> one L2 latency, not 16). The k-loop is then pure LDS reads +
// mfma_i32_16x16x64_i8 (operands swapped: lane&15 = out row, quad*4+reg =
// out col -> float4 stores). x loads / out stores are non-temporal to keep
// L2 dedicated to the 1 MB wqf.
// ---------------------------------------------------------------------------
__global__ __launch_bounds__(256, 4) void tern_gemm_kernel(const float* __restrict__ x,
                                                           const signed char* __restrict__ wqf,
                                                           float* __restrict__ out) {
    __shared__ __attribute__((aligned(16))) signed char a_lds[32 * 1024];
    const int tid = threadIdx.x;
    const long rowbase = (long)blockIdx.x * 32;

    // ---- Phase 1: stage + quantize x slab (32 rows x 1024 K) ----
    #pragma unroll
    for (int i = 0; i < 8; ++i) {
        int c   = tid + i * 256;   // chunk id 0..2047
        int row = c >> 6;          // 64 chunks per row
        int cir = c & 63;          // chunk-in-row
        const floatx4* src = (const floatx4*)(x + (rowbase + row) * 1024 + cir * 16);
        signed char q[16];
        #pragma unroll
        for (int j = 0; j < 4; ++j) {
            floatx4 f = __builtin_nontemporal_load(src + j);
            #pragma unroll
            for (int e = 0; e < 4; ++e)
                q[j * 4 + e] = (signed char)((f[e] >= THRESH) - (f[e] <= -THRESH));
        }
        int swz = (cir ^ (row & 7)) * 16;  // XOR swizzle: uniform bank spread
        *(int32x4*)(a_lds + row * 1024 + swz) = *(const int32x4*)q;
    }
    __syncthreads();

    // ---- Phase 2: compute ----
    const int wave = tid >> 6;    // 0..3
    const int lane = tid & 63;
    const int l15  = lane & 15;
    const int lq   = lane >> 4;   // lane quarter

    for (int colit = 0; colit < 16; ++colit) {
        const int nb = colit * 4 + wave;   // this wave's 16-col tile index

        // B-fragment burst: all 16 K-steps, 16 independent coalesced loads.
        int32x4 bf[16];
        #pragma unroll
        for (int k = 0; k < 16; ++k)
            bf[k] = *(const int32x4*)(wqf + (size_t)(k * 64 + nb) * 1024 + lane * 16);
        __builtin_amdgcn_sched_barrier(0);  // keep the burst ahead of the k-loop

        int32x4 acc[2];
        acc[0] = (int32x4){0, 0, 0, 0};
        acc[1] = (int32x4){0, 0, 0, 0};

        #pragma unroll
        for (int k = 0; k < 16; ++k) {
            const int kchunk = k * 4 + lq;
            #pragma unroll
            for (int ri = 0; ri < 2; ++ri) {
                int m = ri * 16 + l15;
                int32x4 af = *(const int32x4*)(a_lds + m * 1024 + ((kchunk ^ (m & 7)) * 16));
                // swapped operands: D lane&15 = out ROW, quad*4+reg = out COL
                acc[ri] = __builtin_amdgcn_mfma_i32_16x16x64_i8(bf[k], af, acc[ri], 0, 0, 0);
            }
        }

        // ---- epilogue: lane owns 4 consecutive cols -> nt float4 stores ----
        const int cb = colit * 64 + wave * 16;
        #pragma unroll
        for (int ri = 0; ri < 2; ++ri) {
            const long row = rowbase + ri * 16 + l15;
            floatx4 v;
            v[0] = (float)acc[ri][0];
            v[1] = (float)acc[ri][1];
            v[2] = (float)acc[ri][2];
            v[3] = (float)acc[ri][3];
            __builtin_nontemporal_store(v, (floatx4*)(out + row * 1024 + cb + lq * 4));
        }
    }
}

extern "C" void kernel_launch(void* const* d_in, const int* in_sizes, int n_in,
                              void* d_out, int out_size, void* d_ws, size_t ws_size,
                              hipStream_t stream) {
    const float* x = (const float*)d_in[0];      // [32768, 1024] fp32
    const float* w = (const float*)d_in[1];      // [1024, 1024] fp32
    float* out = (float*)d_out;                  // [32768, 1024] fp32
    signed char* wqf = (signed char*)d_ws;       // 1 MB int8 scratch (fragment order)

    quant_w_kernel<<<dim3(256), dim3(256), 0, stream>>>(w, wqf);
    // 32768 rows / 32 = 1024 blocks (4 per CU), 4 waves each
    tern_gemm_kernel<<<dim3(1024), dim3(256), 0, stream>>>(x, wqf, out);
}